// Round 8
// baseline (367.786 us; speedup 1.0000x reference)
//
#include <hip/hip_runtime.h>
#include <cmath>

// Geometry fixed by reference: x,y (16,1,1024,1024) f32, mask (1024,1024) f32, out 1 f32
#define IMG_W   1024
#define IMG_H   1024
#define NIMG    16
#define HW      (1024 * 1024)
#define NHW     (16 * 1024 * 1024)
#define WPR     16                     // 64-bit words per row
#define WPI     (IMG_H * WPR)          // words per image

struct GW { float w[9]; };             // gaussian taps, w[|d|], d in [-8,8]

__device__ __forceinline__ int refl(int v) {        // reflect-101 for 1024
    return v < 0 ? -v : (v > 1023 ? 2046 - v : v);
}

// ------------------------------------------------- vertical blur (x -> vb) ----
__global__ void blur_v(const float* __restrict__ in, float* __restrict__ out, GW g) {
    int gid = blockIdx.x * 256 + threadIdx.x;
    int c4  = gid & 255;
    int rc  = (gid >> 8) & 127;
    const float* img = in  + (size_t)(gid >> 15) * HW;
    float*      outp = out + (size_t)(gid >> 15) * HW;
    int y0 = rc * 8;
    float4 acc[8];
#pragma unroll
    for (int j = 0; j < 8; ++j) acc[j] = make_float4(0.f, 0.f, 0.f, 0.f);
#pragma unroll
    for (int d = -8; d <= 15; ++d) {
        int rr = refl(y0 + d);
        float4 v = *(const float4*)(img + rr * IMG_W + c4 * 4);
#pragma unroll
        for (int j = 0; j < 8; ++j) {
            int k = d - j;
            if (k >= -8 && k <= 8) {
                float wt = g.w[k < 0 ? -k : k];
                acc[j].x += wt * v.x; acc[j].y += wt * v.y;
                acc[j].z += wt * v.z; acc[j].w += wt * v.w;
            }
        }
    }
#pragma unroll
    for (int j = 0; j < 8; ++j)
        *(float4*)(outp + (y0 + j) * IMG_W + c4 * 4) = acc[j];
}

// ---------------------- fused: horizontal blur + sobel + NMS + thresholds ----
// One block per 64x64 output tile. Single LDS buffer L (68 x 88 floats, 23.9KB),
// reused in-place across phases (all writes are regs->barrier->store).
__global__ void __launch_bounds__(256, 5)
hgradnms(const float* __restrict__ vb, unsigned long long* __restrict__ strongw,
         unsigned long long* __restrict__ weakw, GW g) {
    __shared__ float L[68 * 88];                     // 23936 B
    unsigned char* Bn = (unsigned char*)(L + 66 * 68);   // 4488 bytes

    int tid = threadIdx.x;
    int b   = blockIdx.x;
    int img = b >> 8;
    int tr  = (b >> 4) & 15, tc = b & 15;
    int r0  = tr * 64, c0 = tc * 64;
    const float* vimg = vb + (size_t)img * HW;

    // ---- phase 1: gather vb tile ----
    if (tc > 0 && tc < 15) {
        const float* basep = vimg + (c0 - 12);
        for (int i = tid; i < 68 * 22; i += 256) {
            int l = i / 22, q = i % 22;
            int gr = refl(r0 + l - 2);
            *(float4*)(L + l * 88 + 4 * q) = *(const float4*)(basep + gr * IMG_W + 4 * q);
        }
    } else {
        for (int i = tid; i < 68 * 88; i += 256) {
            int l = i / 88, m = i % 88;
            int gr = refl(r0 + l - 2);
            int gc = refl(c0 - 12 + m);
            L[i] = vimg[gr * IMG_W + gc];
        }
    }
    __syncthreads();

    // ---- phase 2: horizontal 17-tap blur (regs -> barrier -> in-place) ----
    float4 oreg[5];
#pragma unroll
    for (int it = 0; it < 5; ++it) {
        int i = tid + it * 256;
        if (i < 68 * 17) {
            int l = i / 17, gq = i % 17;
            float w24[24];
#pragma unroll
            for (int q = 0; q < 6; ++q)
                ((float4*)w24)[q] = *(const float4*)(L + l * 88 + 4 * gq + 4 * q);
            float o0 = 0.f, o1 = 0.f, o2 = 0.f, o3 = 0.f;
#pragma unroll
            for (int t = 0; t < 17; ++t) {
                float wt = g.w[t < 8 ? 8 - t : t - 8];
                o0 += wt * w24[2 + t]; o1 += wt * w24[3 + t];
                o2 += wt * w24[4 + t]; o3 += wt * w24[5 + t];
            }
            oreg[it] = make_float4(o0, o1, o2, o3);
        }
    }
    __syncthreads();
#pragma unroll
    for (int it = 0; it < 5; ++it) {
        int i = tid + it * 256;
        if (i < 68 * 17) {
            int l = i / 17, gq = i % 17;
            *(float4*)(L + l * 88 + 4 * gq) = oreg[it];
        }
    }
    __syncthreads();

    // ---- phase 3: sobel -> mag + bin (regs -> barrier -> overlay M, Bn) ----
    const float T1 = 0.41421356237309503f;   // tan(22.5)
    const float T2 = 2.41421356237309510f;   // tan(67.5)
    float4 mreg[5];
    unsigned int breg[5];
#pragma unroll
    for (int it = 0; it < 5; ++it) {
        int i = tid + it * 256;
        if (i < 66 * 17) {
            int row = i / 17, gq = i % 17;
            float ra[8], rb[8], rc8[8];
            ((float4*)ra)[0]  = *(const float4*)(L + (row    ) * 88 + 4 * gq);
            ((float4*)ra)[1]  = *(const float4*)(L + (row    ) * 88 + 4 * gq + 4);
            ((float4*)rb)[0]  = *(const float4*)(L + (row + 1) * 88 + 4 * gq);
            ((float4*)rb)[1]  = *(const float4*)(L + (row + 1) * 88 + 4 * gq + 4);
            ((float4*)rc8)[0] = *(const float4*)(L + (row + 2) * 88 + 4 * gq);
            ((float4*)rc8)[1] = *(const float4*)(L + (row + 2) * 88 + 4 * gq + 4);
            int pr = r0 + row - 1;
            bool rin = (unsigned)pr <= 1023u;
            float mv[4]; unsigned int bpk = 0;
#pragma unroll
            for (int j = 0; j < 4; ++j) {
                int colidx = 4 * gq + j;
                float a00 = ra[j], a01 = ra[j + 1], a02 = ra[j + 2];
                float a10 = rb[j],                   a12 = rb[j + 2];
                float a20 = rc8[j], a21 = rc8[j + 1], a22 = rc8[j + 2];
                float gx = (a02 - a00) + 2.f * (a12 - a10) + (a22 - a20);
                float gy = (a20 + 2.f * a21 + a22) - (a00 + 2.f * a01 + a02);
                int pc = c0 + colidx - 1;
                bool in = rin && ((unsigned)pc <= 1023u) && (colidx <= 65);
                mv[j] = in ? sqrtf(gx * gx + gy * gy) : 0.f;
                float ax = fabsf(gx), ay = fabsf(gy);
                int bn;
                if (ay < T1 * ax)      bn = 0;
                else if (ay > T2 * ax) bn = 2;
                else                   bn = ((gx > 0.f) == (gy > 0.f)) ? 1 : 3;
                bpk |= (unsigned)bn << (8 * j);
            }
            mreg[it] = make_float4(mv[0], mv[1], mv[2], mv[3]);
            breg[it] = bpk;
        }
    }
    __syncthreads();
#pragma unroll
    for (int it = 0; it < 5; ++it) {
        int i = tid + it * 256;
        if (i < 66 * 17) {
            int row = i / 17, gq = i % 17;
            *(float4*)(L + row * 68 + 4 * gq) = mreg[it];          // M, stride 68
            *(unsigned int*)(Bn + row * 68 + 4 * gq) = breg[it];   // bins
        }
    }
    __syncthreads();

    // ---- phase 4: NMS + thresholds + ballot pack ----
    int lane = tid & 63, wv = tid >> 6;
    unsigned long long* sgw = strongw + (size_t)img * WPI;
    unsigned long long* wkw = weakw   + (size_t)img * WPI;
    for (int it = 0; it < 16; ++it) {
        int qr = wv * 16 + it;
        int qc = lane;
        float cm = L[(qr + 1) * 68 + qc + 1];
        int bn = Bn[(qr + 1) * 68 + qc + 1];
        int d1y = (bn == 0) ? 0 : -1;
        int d1x = (bn < 2) ? 1 : ((bn == 2) ? 0 : -1);
        float n1 = L[(qr + 1 + d1y) * 68 + (qc + 1 + d1x)];
        float n2 = L[(qr + 1 - d1y) * 68 + (qc + 1 - d1x)];
        bool keep   = (cm >= n1) && (cm >= n2);
        bool strong = keep && (cm > 0.2f);
        bool weak   = keep && (cm > 0.1f);
        unsigned long long sb = __ballot(strong);
        unsigned long long wb = __ballot(weak);
        if (lane == 0) {
            int widx = (r0 + qr) * WPR + tc;
            sgw[widx] = sb;
            wkw[widx] = wb;
        }
    }
}

// ------------------------------------------------------------ hysteresis ----
// One block per image; strong bits in 128KB LDS. Dirty-set Gauss-Seidel:
// a word is reprocessed only if its 3x3 word-neighborhood changed last pass
// (ping-ponged per-row dirty bitmasks, atomicOr marking — monotone, benign
// races re-marked by the writer, so the exact reference fixpoint is reached).
__global__ void __launch_bounds__(1024, 1)
hyst(unsigned long long* __restrict__ strongw, const unsigned long long* __restrict__ weakw) {
    __shared__ unsigned long long S[WPI];      // 128 KB
    __shared__ unsigned DbufA[1024];           // dirty masks, bit c = word (r,c)
    __shared__ unsigned DbufB[1024];
    __shared__ int chg;
    unsigned long long* sg = strongw + (size_t)blockIdx.x * WPI;
    const unsigned long long* wk = weakw + (size_t)blockIdx.x * WPI;
    int t = threadIdx.x;
    int c = t & 15;
    int rbase = (t >> 4) * 16;

    unsigned long long ww[16];
#pragma unroll
    for (int i = 0; i < 16; ++i) {
        S[(rbase + i) * WPR + c] = sg[(rbase + i) * WPR + c];
        ww[i] = wk[(rbase + i) * WPR + c];
    }
    DbufA[t] = 0xFFFFu;   // pass 0: everything dirty
    DbufB[t] = 0u;
    __syncthreads();

    unsigned* Dcur = DbufA;
    unsigned* Dnxt = DbufB;

    for (int pass = 0; pass < 4096; ++pass) {
        if (t == 0) chg = 0;
        __syncthreads();
        int any = 0;
        auto step = [&](int r, unsigned long long wwv) {
            if (!((Dcur[r] >> c) & 1u)) return;            // broadcast read
            unsigned long long w = S[r * WPR + c];
            if (!(wwv & ~w)) return;                       // saturated
            unsigned long long up = 0, dn = 0, upl = 0, upr = 0, dnl = 0, dnr = 0, ml = 0, mr = 0;
            if (r > 0)    { up = S[(r - 1) * WPR + c];
                            if (c > 0)  upl = S[(r - 1) * WPR + c - 1];
                            if (c < 15) upr = S[(r - 1) * WPR + c + 1]; }
            if (r < 1023) { dn = S[(r + 1) * WPR + c];
                            if (c > 0)  dnl = S[(r + 1) * WPR + c - 1];
                            if (c < 15) dnr = S[(r + 1) * WPR + c + 1]; }
            if (c > 0)  ml = S[r * WPR + c - 1];
            if (c < 15) mr = S[r * WPR + c + 1];
            unsigned long long H =
                  up | (up << 1) | (up >> 1) | (upl >> 63) | (upr << 63)
                | w  | (w  << 1) | (w  >> 1) | (ml  >> 63) | (mr  << 63)
                | dn | (dn << 1) | (dn >> 1) | (dnl >> 63) | (dnr << 63);
            unsigned long long nw = w | (H & wwv);
            for (;;) {
                unsigned long long nn = nw | (((nw << 1) | (nw >> 1)) & wwv);
                if (nn == nw) break;
                nw = nn;
            }
            if (nw != w) {
                S[r * WPR + c] = nw;
                any = 1;
                unsigned m3 = (7u << c) >> 1;              // cols c-1..c+1 (bit16 never read)
                atomicOr(&Dnxt[r], m3);
                if (r > 0)    atomicOr(&Dnxt[r - 1], m3);
                if (r < 1023) atomicOr(&Dnxt[r + 1], m3);
            }
        };
        if (!(pass & 1)) {
#pragma unroll
            for (int i = 0; i < 16; ++i) step(rbase + i, ww[i]);
        } else {
#pragma unroll
            for (int i = 15; i >= 0; --i) step(rbase + i, ww[i]);
        }
        if (any) chg = 1;
        __syncthreads();
        int done = (chg == 0);
        Dcur[t] = 0u;                     // all reads of Dcur finished; becomes next Dnxt
        unsigned* tmp = Dcur; Dcur = Dnxt; Dnxt = tmp;
        __syncthreads();                  // clears + chg visible before next pass
        if (done) break;
    }
#pragma unroll
    for (int i = 0; i < 16; ++i) sg[(rbase + i) * WPR + c] = S[(rbase + i) * WPR + c];
}

// ------------------------------------------------------------------ loss ----
__global__ void loss_part(const unsigned long long* __restrict__ strongw,
                          const float* __restrict__ y, const float* __restrict__ mask,
                          float* __restrict__ part) {
    int tid = threadIdx.x;
    float local = 0.f;
    const float4* y4 = (const float4*)y;
    const float4* m4 = (const float4*)mask;
    for (int i4 = blockIdx.x * 256 + tid; i4 < NHW / 4; i4 += 2048 * 256) {
        unsigned long long wword = strongw[i4 >> 4];
        int sh = (i4 & 15) * 4;
        unsigned bits = (unsigned)((wword >> sh) & 0xFull);
        float4 yv = y4[i4];
        float4 mv = m4[i4 & (HW / 4 - 1)];
        local += fabsf(((bits & 1u) ? mv.x : 0.f) - yv.x * mv.x);
        local += fabsf(((bits & 2u) ? mv.y : 0.f) - yv.y * mv.y);
        local += fabsf(((bits & 4u) ? mv.z : 0.f) - yv.z * mv.z);
        local += fabsf(((bits & 8u) ? mv.w : 0.f) - yv.w * mv.w);
    }
    for (int off = 32; off; off >>= 1) local += __shfl_down(local, off);
    __shared__ float wsum[4];
    if ((tid & 63) == 0) wsum[tid >> 6] = local;
    __syncthreads();
    if (tid == 0) part[blockIdx.x] = wsum[0] + wsum[1] + wsum[2] + wsum[3];
}

__global__ void loss_final(const float* __restrict__ part, float* __restrict__ out) {
    int tid = threadIdx.x;
    double s = 0.0;
    for (int i = tid; i < 2048; i += 256) s += (double)part[i];
    for (int off = 32; off; off >>= 1) s += __shfl_down(s, off);
    __shared__ double ws4[4];
    if ((tid & 63) == 0) ws4[tid >> 6] = s;
    __syncthreads();
    if (tid == 0) out[0] = (float)((ws4[0] + ws4[1] + ws4[2] + ws4[3]) * (1.0 / (double)HW));
}

// ---------------------------------------------------------------- launch ----
extern "C" void kernel_launch(void* const* d_in, const int* in_sizes, int n_in,
                              void* d_out, int out_size, void* d_ws, size_t ws_size,
                              hipStream_t stream) {
    const float* x    = (const float*)d_in[0];
    const float* y    = (const float*)d_in[1];
    const float* mask = (const float*)d_in[2];
    float* out = (float*)d_out;

    char* ws = (char*)d_ws;
    float* vbuf = (float*)(ws);                                              // 64 MB
    unsigned long long* strongw = (unsigned long long*)(ws + (size_t)64 * 1024 * 1024); // 2 MB
    unsigned long long* weakw   = (unsigned long long*)(ws + (size_t)66 * 1024 * 1024); // 2 MB
    float* part = (float*)(ws + (size_t)68 * 1024 * 1024);                   // 8 KB

    GW g;
    {
        double e[9], s;
        for (int k = 0; k < 9; ++k) e[k] = std::exp(-0.5 * (k / 2.0) * (k / 2.0));
        s = e[0];
        for (int k = 1; k < 9; ++k) s += 2.0 * e[k];
        for (int k = 0; k < 9; ++k) g.w[k] = (float)(e[k] / s);
    }

    blur_v    <<<2048, 256, 0, stream>>>(x, vbuf, g);
    hgradnms  <<<4096, 256, 0, stream>>>(vbuf, strongw, weakw, g);
    hyst      <<<NIMG, 1024, 0, stream>>>(strongw, weakw);
    loss_part <<<2048, 256, 0, stream>>>(strongw, y, mask, part);
    loss_final<<<1, 256, 0, stream>>>(part, out);
}

// Round 9
// 322.779 us; speedup vs baseline: 1.1394x; 1.1394x over previous
//
#include <hip/hip_runtime.h>
#include <cmath>

// Geometry fixed by reference: x,y (16,1,1024,1024) f32, mask (1024,1024) f32, out 1 f32
#define IMG_W   1024
#define IMG_H   1024
#define NIMG    16
#define HW      (1024 * 1024)
#define NHW     (16 * 1024 * 1024)
#define WPR     16                     // 64-bit words per row
#define WPI     (IMG_H * WPR)          // words per image

struct GW { float w[9]; };             // gaussian taps, w[|d|], d in [-8,8]

__device__ __forceinline__ int refl(int v) {        // reflect-101 for 1024
    return v < 0 ? -v : (v > 1023 ? 2046 - v : v);
}

// ------------------------------------------------- vertical blur (x -> vb) ----
__global__ void blur_v(const float* __restrict__ in, float* __restrict__ out, GW g) {
    int gid = blockIdx.x * 256 + threadIdx.x;
    int c4  = gid & 255;
    int rc  = (gid >> 8) & 127;
    const float* img = in  + (size_t)(gid >> 15) * HW;
    float*      outp = out + (size_t)(gid >> 15) * HW;
    int y0 = rc * 8;
    float4 acc[8];
#pragma unroll
    for (int j = 0; j < 8; ++j) acc[j] = make_float4(0.f, 0.f, 0.f, 0.f);
#pragma unroll
    for (int d = -8; d <= 15; ++d) {
        int rr = refl(y0 + d);
        float4 v = *(const float4*)(img + rr * IMG_W + c4 * 4);
#pragma unroll
        for (int j = 0; j < 8; ++j) {
            int k = d - j;
            if (k >= -8 && k <= 8) {
                float wt = g.w[k < 0 ? -k : k];
                acc[j].x += wt * v.x; acc[j].y += wt * v.y;
                acc[j].z += wt * v.z; acc[j].w += wt * v.w;
            }
        }
    }
#pragma unroll
    for (int j = 0; j < 8; ++j)
        *(float4*)(outp + (y0 + j) * IMG_W + c4 * 4) = acc[j];
}

// ---------------------- fused: horizontal blur + sobel + NMS + thresholds ----
// One block per 64x64 output tile. Single LDS buffer L (68 x 88 floats, 23.9KB),
// reused in-place across phases (all writes are regs->barrier->store).
__global__ void __launch_bounds__(256, 5)
hgradnms(const float* __restrict__ vb, unsigned long long* __restrict__ strongw,
         unsigned long long* __restrict__ weakw, GW g) {
    __shared__ float L[68 * 88];                     // 23936 B
    unsigned char* Bn = (unsigned char*)(L + 66 * 68);   // 4488 bytes

    int tid = threadIdx.x;
    int b   = blockIdx.x;
    int img = b >> 8;
    int tr  = (b >> 4) & 15, tc = b & 15;
    int r0  = tr * 64, c0 = tc * 64;
    const float* vimg = vb + (size_t)img * HW;

    // ---- phase 1: gather vb tile ----
    if (tc > 0 && tc < 15) {
        const float* basep = vimg + (c0 - 12);
        for (int i = tid; i < 68 * 22; i += 256) {
            int l = i / 22, q = i % 22;
            int gr = refl(r0 + l - 2);
            *(float4*)(L + l * 88 + 4 * q) = *(const float4*)(basep + gr * IMG_W + 4 * q);
        }
    } else {
        for (int i = tid; i < 68 * 88; i += 256) {
            int l = i / 88, m = i % 88;
            int gr = refl(r0 + l - 2);
            int gc = refl(c0 - 12 + m);
            L[i] = vimg[gr * IMG_W + gc];
        }
    }
    __syncthreads();

    // ---- phase 2: horizontal 17-tap blur (regs -> barrier -> in-place) ----
    float4 oreg[5];
#pragma unroll
    for (int it = 0; it < 5; ++it) {
        int i = tid + it * 256;
        if (i < 68 * 17) {
            int l = i / 17, gq = i % 17;
            float w24[24];
#pragma unroll
            for (int q = 0; q < 6; ++q)
                ((float4*)w24)[q] = *(const float4*)(L + l * 88 + 4 * gq + 4 * q);
            float o0 = 0.f, o1 = 0.f, o2 = 0.f, o3 = 0.f;
#pragma unroll
            for (int t = 0; t < 17; ++t) {
                float wt = g.w[t < 8 ? 8 - t : t - 8];
                o0 += wt * w24[2 + t]; o1 += wt * w24[3 + t];
                o2 += wt * w24[4 + t]; o3 += wt * w24[5 + t];
            }
            oreg[it] = make_float4(o0, o1, o2, o3);
        }
    }
    __syncthreads();
#pragma unroll
    for (int it = 0; it < 5; ++it) {
        int i = tid + it * 256;
        if (i < 68 * 17) {
            int l = i / 17, gq = i % 17;
            *(float4*)(L + l * 88 + 4 * gq) = oreg[it];
        }
    }
    __syncthreads();

    // ---- phase 3: sobel -> mag + bin (regs -> barrier -> overlay M, Bn) ----
    const float T1 = 0.41421356237309503f;   // tan(22.5)
    const float T2 = 2.41421356237309510f;   // tan(67.5)
    float4 mreg[5];
    unsigned int breg[5];
#pragma unroll
    for (int it = 0; it < 5; ++it) {
        int i = tid + it * 256;
        if (i < 66 * 17) {
            int row = i / 17, gq = i % 17;
            float ra[8], rb[8], rc8[8];
            ((float4*)ra)[0]  = *(const float4*)(L + (row    ) * 88 + 4 * gq);
            ((float4*)ra)[1]  = *(const float4*)(L + (row    ) * 88 + 4 * gq + 4);
            ((float4*)rb)[0]  = *(const float4*)(L + (row + 1) * 88 + 4 * gq);
            ((float4*)rb)[1]  = *(const float4*)(L + (row + 1) * 88 + 4 * gq + 4);
            ((float4*)rc8)[0] = *(const float4*)(L + (row + 2) * 88 + 4 * gq);
            ((float4*)rc8)[1] = *(const float4*)(L + (row + 2) * 88 + 4 * gq + 4);
            int pr = r0 + row - 1;
            bool rin = (unsigned)pr <= 1023u;
            float mv[4]; unsigned int bpk = 0;
#pragma unroll
            for (int j = 0; j < 4; ++j) {
                int colidx = 4 * gq + j;
                float a00 = ra[j], a01 = ra[j + 1], a02 = ra[j + 2];
                float a10 = rb[j],                   a12 = rb[j + 2];
                float a20 = rc8[j], a21 = rc8[j + 1], a22 = rc8[j + 2];
                float gx = (a02 - a00) + 2.f * (a12 - a10) + (a22 - a20);
                float gy = (a20 + 2.f * a21 + a22) - (a00 + 2.f * a01 + a02);
                int pc = c0 + colidx - 1;
                bool in = rin && ((unsigned)pc <= 1023u) && (colidx <= 65);
                mv[j] = in ? sqrtf(gx * gx + gy * gy) : 0.f;
                float ax = fabsf(gx), ay = fabsf(gy);
                int bn;
                if (ay < T1 * ax)      bn = 0;
                else if (ay > T2 * ax) bn = 2;
                else                   bn = ((gx > 0.f) == (gy > 0.f)) ? 1 : 3;
                bpk |= (unsigned)bn << (8 * j);
            }
            mreg[it] = make_float4(mv[0], mv[1], mv[2], mv[3]);
            breg[it] = bpk;
        }
    }
    __syncthreads();
#pragma unroll
    for (int it = 0; it < 5; ++it) {
        int i = tid + it * 256;
        if (i < 66 * 17) {
            int row = i / 17, gq = i % 17;
            *(float4*)(L + row * 68 + 4 * gq) = mreg[it];          // M, stride 68
            *(unsigned int*)(Bn + row * 68 + 4 * gq) = breg[it];   // bins
        }
    }
    __syncthreads();

    // ---- phase 4: NMS + thresholds + ballot pack ----
    int lane = tid & 63, wv = tid >> 6;
    unsigned long long* sgw = strongw + (size_t)img * WPI;
    unsigned long long* wkw = weakw   + (size_t)img * WPI;
    for (int it = 0; it < 16; ++it) {
        int qr = wv * 16 + it;
        int qc = lane;
        float cm = L[(qr + 1) * 68 + qc + 1];
        int bn = Bn[(qr + 1) * 68 + qc + 1];
        int d1y = (bn == 0) ? 0 : -1;
        int d1x = (bn < 2) ? 1 : ((bn == 2) ? 0 : -1);
        float n1 = L[(qr + 1 + d1y) * 68 + (qc + 1 + d1x)];
        float n2 = L[(qr + 1 - d1y) * 68 + (qc + 1 - d1x)];
        bool keep   = (cm >= n1) && (cm >= n2);
        bool strong = keep && (cm > 0.2f);
        bool weak   = keep && (cm > 0.1f);
        unsigned long long sb = __ballot(strong);
        unsigned long long wb = __ballot(weak);
        if (lane == 0) {
            int widx = (r0 + qr) * WPR + tc;
            sgw[widx] = sb;
            wkw[widx] = wb;
        }
    }
}

// ---------------------------------------- strip-parallel hysteresis pre-pass ----
// 256 blocks = 16 images x 16 strips of 64 rows; 1 word/thread. Local
// Gauss-Seidel to strip-local fixpoint in LDS with frozen halo rows (a
// consistent snapshot: stream-serialized launches). Monotone sound
// under-approximation of the true fixpoint; exactness guaranteed by the
// final single-block solver.
__global__ void __launch_bounds__(1024, 1)
hyst_strip(unsigned long long* __restrict__ strongw, const unsigned long long* __restrict__ weakw) {
    __shared__ unsigned long long S[66 * WPR];   // rows -1..64 (halo top/bottom), 8448 B
    __shared__ int chg;
    int img = blockIdx.x >> 4, st = blockIdx.x & 15;
    int r0 = st * 64;
    unsigned long long* sg = strongw + (size_t)img * WPI;
    const unsigned long long* wk = weakw + (size_t)img * WPI;
    int t = threadIdx.x;
    int c = t & 15, lr = t >> 4;                 // local row 0..63
    int r = lr + 1;                              // LDS row index

    S[r * WPR + c] = sg[(r0 + lr) * WPR + c];
    unsigned long long ww = wk[(r0 + lr) * WPR + c];
    if (t < WPR)
        S[t] = (r0 > 0) ? sg[(r0 - 1) * WPR + t] : 0ull;
    else if (t < 2 * WPR)
        S[65 * WPR + (t - WPR)] = (r0 + 64 < IMG_H) ? sg[(r0 + 64) * WPR + (t - WPR)] : 0ull;
    __syncthreads();

    for (int pass = 0; pass < 512; ++pass) {
        if (t == 0) chg = 0;
        __syncthreads();
        int any = 0;
        unsigned long long w = S[r * WPR + c];
        if (ww & ~w) {
            unsigned long long up = S[(r - 1) * WPR + c];
            unsigned long long dn = S[(r + 1) * WPR + c];
            unsigned long long upl = (c > 0)  ? S[(r - 1) * WPR + c - 1] : 0ull;
            unsigned long long upr = (c < 15) ? S[(r - 1) * WPR + c + 1] : 0ull;
            unsigned long long dnl = (c > 0)  ? S[(r + 1) * WPR + c - 1] : 0ull;
            unsigned long long dnr = (c < 15) ? S[(r + 1) * WPR + c + 1] : 0ull;
            unsigned long long ml  = (c > 0)  ? S[r * WPR + c - 1] : 0ull;
            unsigned long long mr  = (c < 15) ? S[r * WPR + c + 1] : 0ull;
            unsigned long long H =
                  up | (up << 1) | (up >> 1) | (upl >> 63) | (upr << 63)
                | w  | (w  << 1) | (w  >> 1) | (ml  >> 63) | (mr  << 63)
                | dn | (dn << 1) | (dn >> 1) | (dnl >> 63) | (dnr << 63);
            unsigned long long nw = w | (H & ww);
            for (;;) {
                unsigned long long nn = nw | (((nw << 1) | (nw >> 1)) & ww);
                if (nn == nw) break;
                nw = nn;
            }
            if (nw != w) { S[r * WPR + c] = nw; any = 1; }
        }
        if (any) chg = 1;
        __syncthreads();
        int done = (chg == 0);
        __syncthreads();
        if (done) break;
    }
    sg[(r0 + lr) * WPR + c] = S[r * WPR + c];
}

// ------------------------------------------------------------ hysteresis ----
// One block per image; strong bits in 128KB LDS; zigzag Gauss-Seidel sweeps
// to the exact reference fixpoint (R7-proven version, dirty machinery removed).
__global__ void __launch_bounds__(1024, 1)
hyst(unsigned long long* __restrict__ strongw, const unsigned long long* __restrict__ weakw) {
    __shared__ unsigned long long S[WPI];
    __shared__ int chg;
    unsigned long long* sg = strongw + (size_t)blockIdx.x * WPI;
    const unsigned long long* wk = weakw + (size_t)blockIdx.x * WPI;
    int t = threadIdx.x;
    int c = t & 15;
    int rbase = (t >> 4) * 16;

    unsigned long long ww[16];
#pragma unroll
    for (int i = 0; i < 16; ++i) {
        S[(rbase + i) * WPR + c] = sg[(rbase + i) * WPR + c];
        ww[i] = wk[(rbase + i) * WPR + c];
    }
    __syncthreads();

    for (int pass = 0; pass < 4096; ++pass) {
        if (t == 0) chg = 0;
        __syncthreads();
        int any = 0;
        auto step = [&](int r, unsigned long long wwv) {
            unsigned long long w = S[r * WPR + c];
            if (!(wwv & ~w)) return;
            unsigned long long up = 0, dn = 0, upl = 0, upr = 0, dnl = 0, dnr = 0, ml = 0, mr = 0;
            if (r > 0)    { up = S[(r - 1) * WPR + c];
                            if (c > 0)  upl = S[(r - 1) * WPR + c - 1];
                            if (c < 15) upr = S[(r - 1) * WPR + c + 1]; }
            if (r < 1023) { dn = S[(r + 1) * WPR + c];
                            if (c > 0)  dnl = S[(r + 1) * WPR + c - 1];
                            if (c < 15) dnr = S[(r + 1) * WPR + c + 1]; }
            if (c > 0)  ml = S[r * WPR + c - 1];
            if (c < 15) mr = S[r * WPR + c + 1];
            unsigned long long H =
                  up | (up << 1) | (up >> 1) | (upl >> 63) | (upr << 63)
                | w  | (w  << 1) | (w  >> 1) | (ml  >> 63) | (mr  << 63)
                | dn | (dn << 1) | (dn >> 1) | (dnl >> 63) | (dnr << 63);
            unsigned long long nw = w | (H & wwv);
            for (;;) {
                unsigned long long nn = nw | (((nw << 1) | (nw >> 1)) & wwv);
                if (nn == nw) break;
                nw = nn;
            }
            if (nw != w) { S[r * WPR + c] = nw; any = 1; }
        };
        if (!(pass & 1)) {
#pragma unroll
            for (int i = 0; i < 16; ++i) step(rbase + i, ww[i]);
        } else {
#pragma unroll
            for (int i = 15; i >= 0; --i) step(rbase + i, ww[i]);
        }
        if (any) chg = 1;
        __syncthreads();
        int done = (chg == 0);
        __syncthreads();
        if (done) break;
    }
#pragma unroll
    for (int i = 0; i < 16; ++i) sg[(rbase + i) * WPR + c] = S[(rbase + i) * WPR + c];
}

// ------------------------------------------------------------------ loss ----
__global__ void loss_part(const unsigned long long* __restrict__ strongw,
                          const float* __restrict__ y, const float* __restrict__ mask,
                          float* __restrict__ part) {
    int tid = threadIdx.x;
    float local = 0.f;
    const float4* y4 = (const float4*)y;
    const float4* m4 = (const float4*)mask;
    for (int i4 = blockIdx.x * 256 + tid; i4 < NHW / 4; i4 += 2048 * 256) {
        unsigned long long wword = strongw[i4 >> 4];
        int sh = (i4 & 15) * 4;
        unsigned bits = (unsigned)((wword >> sh) & 0xFull);
        float4 yv = y4[i4];
        float4 mv = m4[i4 & (HW / 4 - 1)];
        local += fabsf(((bits & 1u) ? mv.x : 0.f) - yv.x * mv.x);
        local += fabsf(((bits & 2u) ? mv.y : 0.f) - yv.y * mv.y);
        local += fabsf(((bits & 4u) ? mv.z : 0.f) - yv.z * mv.z);
        local += fabsf(((bits & 8u) ? mv.w : 0.f) - yv.w * mv.w);
    }
    for (int off = 32; off; off >>= 1) local += __shfl_down(local, off);
    __shared__ float wsum[4];
    if ((tid & 63) == 0) wsum[tid >> 6] = local;
    __syncthreads();
    if (tid == 0) part[blockIdx.x] = wsum[0] + wsum[1] + wsum[2] + wsum[3];
}

__global__ void loss_final(const float* __restrict__ part, float* __restrict__ out) {
    int tid = threadIdx.x;
    double s = 0.0;
    for (int i = tid; i < 2048; i += 256) s += (double)part[i];
    for (int off = 32; off; off >>= 1) s += __shfl_down(s, off);
    __shared__ double ws4[4];
    if ((tid & 63) == 0) ws4[tid >> 6] = s;
    __syncthreads();
    if (tid == 0) out[0] = (float)((ws4[0] + ws4[1] + ws4[2] + ws4[3]) * (1.0 / (double)HW));
}

// ---------------------------------------------------------------- launch ----
extern "C" void kernel_launch(void* const* d_in, const int* in_sizes, int n_in,
                              void* d_out, int out_size, void* d_ws, size_t ws_size,
                              hipStream_t stream) {
    const float* x    = (const float*)d_in[0];
    const float* y    = (const float*)d_in[1];
    const float* mask = (const float*)d_in[2];
    float* out = (float*)d_out;

    char* ws = (char*)d_ws;
    float* vbuf = (float*)(ws);                                              // 64 MB
    unsigned long long* strongw = (unsigned long long*)(ws + (size_t)64 * 1024 * 1024); // 2 MB
    unsigned long long* weakw   = (unsigned long long*)(ws + (size_t)66 * 1024 * 1024); // 2 MB
    float* part = (float*)(ws + (size_t)68 * 1024 * 1024);                   // 8 KB

    GW g;
    {
        double e[9], s;
        for (int k = 0; k < 9; ++k) e[k] = std::exp(-0.5 * (k / 2.0) * (k / 2.0));
        s = e[0];
        for (int k = 1; k < 9; ++k) s += 2.0 * e[k];
        for (int k = 0; k < 9; ++k) g.w[k] = (float)(e[k] / s);
    }

    blur_v    <<<2048, 256, 0, stream>>>(x, vbuf, g);
    hgradnms  <<<4096, 256, 0, stream>>>(vbuf, strongw, weakw, g);
    hyst_strip<<<NIMG * 16, 1024, 0, stream>>>(strongw, weakw);   // bulk flood, all CUs
    hyst_strip<<<NIMG * 16, 1024, 0, stream>>>(strongw, weakw);   // cross-boundary round
    hyst      <<<NIMG, 1024, 0, stream>>>(strongw, weakw);        // exact fixpoint
    loss_part <<<2048, 256, 0, stream>>>(strongw, y, mask, part);
    loss_final<<<1, 256, 0, stream>>>(part, out);
}